// Round 6
// baseline (90.979 us; speedup 1.0000x reference)
//
#include <hip/hip_runtime.h>

#define NCLASS 100
#define HID    768
#define BATCH  512
#define SG     8
#define NPAN   12      // 12 panels of 64 columns/rows

// Deterministic per-class sample list (wave 0 of each block).
__device__ __forceinline__ void build_list(const int* __restrict__ y, int c,
                                           int* slist, int* scnt, int t) {
    if (t < 64) {
        int n = 0;
        for (int r = 0; r < BATCH / 64; ++r) {
            const int b = r * 64 + t;
            const bool hit = (y[b] == c);
            const unsigned long long mask = __ballot(hit);
            if (hit) slist[n + __popcll(mask & ((1ull << t) - 1ull))] = b;
            n += __popcll(mask);
        }
        if (t == 0) *scnt = n;
    }
}

// ---------------------------------------------------------------------------
// Kernel A: t[b, j] for j in 64-col panel J=[64g, 64g+64), b in class c.
//   t_j = sum_{h<j} x_h M[h,j] + d_j x_j + 1e-3 (X - x_j), d_j=max(M[j,j],1e-3)
// Bulk rows (h < col0) stream branch-free in 128-row chunks with 8 float4
// loads hoisted (8-deep MLP); the diagonal 64-row square is peeled + masked.
// Thread map: hg = t>>4 (16 rows/chunk), jq = t&15 (16 col-quads).
// ---------------------------------------------------------------------------
__global__ __launch_bounds__(256, 4) void kA(
    const float* __restrict__ x, const int* __restrict__ y,
    const float* __restrict__ M, float* __restrict__ T)
{
    const int c    = blockIdx.x;
    const int g    = (NPAN - 1) - blockIdx.y;   // big panels dispatch first
    const int t    = threadIdx.x;
    const int col0 = g * 64;

    __shared__ int   slist[BATCH];
    __shared__ int   scnt;
    __shared__ float xs[SG][HID];            // 24 KB
    __shared__ float Xs[SG];
    __shared__ float red[4][16][4][SG + 1];  // padded: 2-way banks on write
    __shared__ float dj_lds[64];

    build_list(y, c, slist, &scnt, t);
    __syncthreads();
    const int cnt = scnt;
    if (cnt == 0) return;

    const float* __restrict__ Mc   = M + (size_t)c * HID * HID;
    const float* __restrict__ Mpan = Mc + col0 + (t & 15) * 4;
    const int wv = t >> 6, ln = t & 63;
    const int hg = t >> 4, jq = t & 15;

    if (t < 64) {
        const int jg = col0 + t;
        dj_lds[t] = fmaxf(Mc[(size_t)jg * HID + jg], 1e-3f);
    }

    for (int g0 = 0; g0 < cnt; g0 += SG) {
        const int gs = min(SG, cnt - g0);
        __syncthreads();                      // prev group done; dj_lds visible
        // stage x rows: wave wv stages samples 2wv, 2wv+1; also row-sums X
        #pragma unroll
        for (int ss = 0; ss < 2; ++ss) {
            const int s = 2 * wv + ss;
            const int b = slist[g0 + (s < gs ? s : 0)];
            const float4* xr = (const float4*)(x + (size_t)b * HID);
            const float4 v0 = xr[ln], v1 = xr[ln + 64], v2 = xr[ln + 128];
            *(float4*)&xs[s][ln * 4]       = v0;
            *(float4*)&xs[s][ln * 4 + 256] = v1;
            *(float4*)&xs[s][ln * 4 + 512] = v2;
            float pX = ((v0.x + v0.y) + (v0.z + v0.w))
                     + ((v1.x + v1.y) + (v1.z + v1.w))
                     + ((v2.x + v2.y) + (v2.z + v2.w));
            #pragma unroll
            for (int off = 32; off; off >>= 1) pX += __shfl_xor(pX, off);
            if (ln == 0) Xs[s] = pX;
        }
        __syncthreads();                      // xs, Xs visible

        float tp[4][SG];
        #pragma unroll
        for (int jj = 0; jj < 4; ++jj)
            #pragma unroll
            for (int s = 0; s < SG; ++s) tp[jj][s] = 0.f;

        // ---- bulk: branch-free, 128 rows/iter, 8 loads in flight ----
        int hb = 0;
        for (; hb + 128 <= col0; hb += 128) {
            float4 ma[4], mb[4];
            #pragma unroll
            for (int m = 0; m < 4; ++m)
                ma[m] = *(const float4*)(Mpan + (size_t)(hb + hg + 16 * m) * HID);
            #pragma unroll
            for (int m = 0; m < 4; ++m)
                mb[m] = *(const float4*)(Mpan + (size_t)(hb + 64 + hg + 16 * m) * HID);
            #pragma unroll
            for (int m = 0; m < 4; ++m) {
                const int h = hb + hg + 16 * m;
                #pragma unroll
                for (int s = 0; s < SG; ++s) {
                    const float xv = xs[s][h];
                    tp[0][s] = fmaf(xv, ma[m].x, tp[0][s]);
                    tp[1][s] = fmaf(xv, ma[m].y, tp[1][s]);
                    tp[2][s] = fmaf(xv, ma[m].z, tp[2][s]);
                    tp[3][s] = fmaf(xv, ma[m].w, tp[3][s]);
                }
            }
            #pragma unroll
            for (int m = 0; m < 4; ++m) {
                const int h = hb + 64 + hg + 16 * m;
                #pragma unroll
                for (int s = 0; s < SG; ++s) {
                    const float xv = xs[s][h];
                    tp[0][s] = fmaf(xv, mb[m].x, tp[0][s]);
                    tp[1][s] = fmaf(xv, mb[m].y, tp[1][s]);
                    tp[2][s] = fmaf(xv, mb[m].z, tp[2][s]);
                    tp[3][s] = fmaf(xv, mb[m].w, tp[3][s]);
                }
            }
        }
        if (hb < col0) {                      // single remaining bulk chunk
            float4 ma[4];
            #pragma unroll
            for (int m = 0; m < 4; ++m)
                ma[m] = *(const float4*)(Mpan + (size_t)(hb + hg + 16 * m) * HID);
            #pragma unroll
            for (int m = 0; m < 4; ++m) {
                const int h = hb + hg + 16 * m;
                #pragma unroll
                for (int s = 0; s < SG; ++s) {
                    const float xv = xs[s][h];
                    tp[0][s] = fmaf(xv, ma[m].x, tp[0][s]);
                    tp[1][s] = fmaf(xv, ma[m].y, tp[1][s]);
                    tp[2][s] = fmaf(xv, ma[m].z, tp[2][s]);
                    tp[3][s] = fmaf(xv, ma[m].w, tp[3][s]);
                }
            }
        }
        // ---- peeled diagonal 64-row square: strict h<j masks ----
        {
            float4 ma[4];
            #pragma unroll
            for (int m = 0; m < 4; ++m) {
                const int hrel = hg + 16 * m;
                ma[m] = *(const float4*)(Mpan + (size_t)(col0 + hrel) * HID);
                if (4 * jq + 0 <= hrel) ma[m].x = 0.f;
                if (4 * jq + 1 <= hrel) ma[m].y = 0.f;
                if (4 * jq + 2 <= hrel) ma[m].z = 0.f;
                if (4 * jq + 3 <= hrel) ma[m].w = 0.f;
            }
            #pragma unroll
            for (int m = 0; m < 4; ++m) {
                const int h = col0 + hg + 16 * m;
                #pragma unroll
                for (int s = 0; s < SG; ++s) {
                    const float xv = xs[s][h];
                    tp[0][s] = fmaf(xv, ma[m].x, tp[0][s]);
                    tp[1][s] = fmaf(xv, ma[m].y, tp[1][s]);
                    tp[2][s] = fmaf(xv, ma[m].z, tp[2][s]);
                    tp[3][s] = fmaf(xv, ma[m].w, tp[3][s]);
                }
            }
        }
        // reduce the 4 row-groups within each wave (lane bits 4,5)
        #pragma unroll
        for (int m = 16; m <= 32; m <<= 1)
            #pragma unroll
            for (int jj = 0; jj < 4; ++jj)
                #pragma unroll
                for (int s = 0; s < SG; ++s)
                    tp[jj][s] += __shfl_xor(tp[jj][s], m);
        if (ln < 16) {
            #pragma unroll
            for (int jj = 0; jj < 4; ++jj)
                #pragma unroll
                for (int s = 0; s < SG; ++s)
                    red[wv][ln][jj][s] = tp[jj][s];
        }
        __syncthreads();                      // red visible
        // finalize: thread t handles col j = t&63 for 2 samples
        {
            const int j = t & 63, jq2 = j >> 2, jj2 = j & 3;
            const int jg = col0 + j;
            #pragma unroll
            for (int ss = 0; ss < 2; ++ss) {
                const int s = (t >> 6) * 2 + ss;
                if (s < gs) {
                    const float u = (red[0][jq2][jj2][s] + red[1][jq2][jj2][s])
                                  + (red[2][jq2][jj2][s] + red[3][jq2][jj2][s]);
                    const float xj = xs[s][jg];
                    T[(size_t)slist[g0 + s] * HID + jg] =
                        u + dj_lds[j] * xj + 1e-3f * (Xs[s] - xj);
                }
            }
        }
    }
}

// ---------------------------------------------------------------------------
// Kernel B: out[b, k] for k in 64-row panel K=[64q, 64q+64), b in class c.
//   out_k = sum_{j>k} M[k,j] t_j + d_k t_k + 1e-3 (Tt - t_k)
// Diag-crossing 64-col chunk peeled + masked; bulk streams branch-free in
// 128-col chunks with 8 float4 loads hoisted.
// Thread map: kr = t>>4 (16 rows x 4 m-chunks), cg = t&15 (16 col-quads).
// NOTE: row base pointers include the panel column offset k0 (round-5 bug).
// ---------------------------------------------------------------------------
__global__ __launch_bounds__(256, 4) void kB(
    const int* __restrict__ y, const float* __restrict__ M,
    const float* __restrict__ T, float* __restrict__ out)
{
    const int c  = blockIdx.x;
    const int q  = blockIdx.y;                // q=0 (biggest) first
    const int t  = threadIdx.x;
    const int k0 = q * 64;

    __shared__ int   slist[BATCH];
    __shared__ int   scnt;
    __shared__ float ts[SG][HID];             // 24 KB
    __shared__ float Tt[SG];
    __shared__ float ob[SG][64];
    __shared__ float dk_lds[64];

    build_list(y, c, slist, &scnt, t);
    __syncthreads();
    const int cnt = scnt;
    if (cnt == 0) return;

    const float* __restrict__ Mc = M + (size_t)c * HID * HID;
    const int wv = t >> 6, ln = t & 63;
    const int kr = t >> 4, cg = t & 15;
    // per-thread row base pointers for the 4 owned rows (at panel col k0)
    const float* __restrict__ r0 = Mc + (size_t)(k0 + kr     ) * HID + k0 + cg * 4;
    const float* __restrict__ r1 = Mc + (size_t)(k0 + kr + 16) * HID + k0 + cg * 4;
    const float* __restrict__ r2 = Mc + (size_t)(k0 + kr + 32) * HID + k0 + cg * 4;
    const float* __restrict__ r3 = Mc + (size_t)(k0 + kr + 48) * HID + k0 + cg * 4;

    if (t < 64) {
        const int kg = k0 + t;
        dk_lds[t] = fmaxf(Mc[(size_t)kg * HID + kg], 1e-3f);
    }

    for (int g0 = 0; g0 < cnt; g0 += SG) {
        const int gs = min(SG, cnt - g0);
        __syncthreads();                      // prev group done (ob reads done)
        // stage t rows: wave wv stages samples 2wv, 2wv+1; also row-sums Tt
        #pragma unroll
        for (int ss = 0; ss < 2; ++ss) {
            const int s = 2 * wv + ss;
            const int b = slist[g0 + (s < gs ? s : 0)];
            const float4* tr = (const float4*)(T + (size_t)b * HID);
            const float4 v0 = tr[ln], v1 = tr[ln + 64], v2 = tr[ln + 128];
            *(float4*)&ts[s][ln * 4]       = v0;
            *(float4*)&ts[s][ln * 4 + 256] = v1;
            *(float4*)&ts[s][ln * 4 + 512] = v2;
            float pT = ((v0.x + v0.y) + (v0.z + v0.w))
                     + ((v1.x + v1.y) + (v1.z + v1.w))
                     + ((v2.x + v2.y) + (v2.z + v2.w));
            #pragma unroll
            for (int off = 32; off; off >>= 1) pT += __shfl_xor(pT, off);
            if (ln == 0) Tt[s] = pT;
        }
        __syncthreads();                      // ts, Tt visible

        float acc[4][SG];
        #pragma unroll
        for (int m = 0; m < 4; ++m)
            #pragma unroll
            for (int s = 0; s < SG; ++s) acc[m][s] = 0.f;

        // ---- peeled diag-crossing chunk (jb = k0): keep j>k only ----
        {
            const int j0 = k0 + cg * 4;
            float4 mq[4];
            mq[0] = *(const float4*)(r0);
            mq[1] = *(const float4*)(r1);
            mq[2] = *(const float4*)(r2);
            mq[3] = *(const float4*)(r3);
            #pragma unroll
            for (int m = 0; m < 4; ++m) {
                const int k = k0 + 16 * m + kr;
                if (j0 + 0 <= k) mq[m].x = 0.f;
                if (j0 + 1 <= k) mq[m].y = 0.f;
                if (j0 + 2 <= k) mq[m].z = 0.f;
                if (j0 + 3 <= k) mq[m].w = 0.f;
            }
            #pragma unroll
            for (int s = 0; s < SG; ++s) {
                const float4 tv = *(const float4*)&ts[s][j0];
                #pragma unroll
                for (int m = 0; m < 4; ++m) {
                    acc[m][s] = fmaf(mq[m].x, tv.x, acc[m][s]);
                    acc[m][s] = fmaf(mq[m].y, tv.y, acc[m][s]);
                    acc[m][s] = fmaf(mq[m].z, tv.z, acc[m][s]);
                    acc[m][s] = fmaf(mq[m].w, tv.w, acc[m][s]);
                }
            }
        }
        // ---- bulk: branch-free, 128 cols/iter, 8 loads in flight ----
        int jb = k0 + 64;
        for (; jb + 128 <= HID; jb += 128) {
            float4 ma[4], mb[4];
            ma[0] = *(const float4*)(r0 + (jb - k0));
            ma[1] = *(const float4*)(r1 + (jb - k0));
            ma[2] = *(const float4*)(r2 + (jb - k0));
            ma[3] = *(const float4*)(r3 + (jb - k0));
            mb[0] = *(const float4*)(r0 + (jb - k0) + 64);
            mb[1] = *(const float4*)(r1 + (jb - k0) + 64);
            mb[2] = *(const float4*)(r2 + (jb - k0) + 64);
            mb[3] = *(const float4*)(r3 + (jb - k0) + 64);
            const int j0 = jb + cg * 4;
            #pragma unroll
            for (int s = 0; s < SG; ++s) {
                const float4 tv = *(const float4*)&ts[s][j0];
                #pragma unroll
                for (int m = 0; m < 4; ++m) {
                    acc[m][s] = fmaf(ma[m].x, tv.x, acc[m][s]);
                    acc[m][s] = fmaf(ma[m].y, tv.y, acc[m][s]);
                    acc[m][s] = fmaf(ma[m].z, tv.z, acc[m][s]);
                    acc[m][s] = fmaf(ma[m].w, tv.w, acc[m][s]);
                }
            }
            #pragma unroll
            for (int s = 0; s < SG; ++s) {
                const float4 tv = *(const float4*)&ts[s][j0 + 64];
                #pragma unroll
                for (int m = 0; m < 4; ++m) {
                    acc[m][s] = fmaf(mb[m].x, tv.x, acc[m][s]);
                    acc[m][s] = fmaf(mb[m].y, tv.y, acc[m][s]);
                    acc[m][s] = fmaf(mb[m].z, tv.z, acc[m][s]);
                    acc[m][s] = fmaf(mb[m].w, tv.w, acc[m][s]);
                }
            }
        }
        if (jb < HID) {                       // single remaining chunk
            float4 ma[4];
            ma[0] = *(const float4*)(r0 + (jb - k0));
            ma[1] = *(const float4*)(r1 + (jb - k0));
            ma[2] = *(const float4*)(r2 + (jb - k0));
            ma[3] = *(const float4*)(r3 + (jb - k0));
            const int j0 = jb + cg * 4;
            #pragma unroll
            for (int s = 0; s < SG; ++s) {
                const float4 tv = *(const float4*)&ts[s][j0];
                #pragma unroll
                for (int m = 0; m < 4; ++m) {
                    acc[m][s] = fmaf(ma[m].x, tv.x, acc[m][s]);
                    acc[m][s] = fmaf(ma[m].y, tv.y, acc[m][s]);
                    acc[m][s] = fmaf(ma[m].z, tv.z, acc[m][s]);
                    acc[m][s] = fmaf(ma[m].w, tv.w, acc[m][s]);
                }
            }
        }
        // reduce over the 16 col-quads (lane bits 0..3)
        #pragma unroll
        for (int m2 = 1; m2 <= 8; m2 <<= 1)
            #pragma unroll
            for (int m = 0; m < 4; ++m)
                #pragma unroll
                for (int s = 0; s < SG; ++s)
                    acc[m][s] += __shfl_xor(acc[m][s], m2);
        if (cg == 0) {
            #pragma unroll
            for (int m = 0; m < 4; ++m)
                #pragma unroll
                for (int s = 0; s < SG; ++s)
                    ob[s][16 * m + kr] = acc[m][s];
        }
        __syncthreads();                      // ob visible
        // store: thread t handles k = k0 + (t&63) for 2 samples
        {
            const int j = t & 63;
            const int k = k0 + j;
            #pragma unroll
            for (int ss = 0; ss < 2; ++ss) {
                const int s = (t >> 6) * 2 + ss;
                if (s < gs) {
                    const float tk = ts[s][k];
                    out[(size_t)slist[g0 + s] * HID + k] =
                        ob[s][j] + dk_lds[j] * tk + 1e-3f * (Tt[s] - tk);
                }
            }
        }
    }
}

extern "C" void kernel_launch(void* const* d_in, const int* in_sizes, int n_in,
                              void* d_out, int out_size, void* d_ws, size_t ws_size,
                              hipStream_t stream) {
    const float* x = (const float*)d_in[0];
    const int*   y = (const int*)d_in[1];
    const float* M = (const float*)d_in[2];
    float* out = (float*)d_out;
    float* T   = (float*)d_ws;   // 512 * 768 * 4 B = 1.5 MiB scratch

    kA<<<dim3(NCLASS, NPAN), 256, 0, stream>>>(x, y, M, T);
    kB<<<dim3(NCLASS, NPAN), 256, 0, stream>>>(y, M, T, out);
}